// Round 12
// baseline (552.690 us; speedup 1.0000x reference)
//
#include <hip/hip_runtime.h>

typedef unsigned short u16;
typedef __bf16 bf16x8 __attribute__((ext_vector_type(8)));
typedef float f32x4 __attribute__((ext_vector_type(4)));
typedef u16 u16x8 __attribute__((ext_vector_type(8)));
typedef u16 u16x4 __attribute__((ext_vector_type(4)));

#define TM 64
#define LDP 264          // padded LDS row stride (elems)
#define BTOT 32768

// bf16 frag-swizzled weight layout inside d_ws (element offsets)
#define OFF_WIH 0
#define OFF_WHH 524288
#define OFF_WQ  786432
#define OFF_WK  851968
#define OFF_WBA 917504
#define OFF_WAT 1179648
#define OFF_WP1 1310720
#define OFF_WP2 1343488
#define OFF_WV1 1351680
#define OFF_WV2 1368064
#define OFF_G   1370112   // precomputed gate table: 4 x 256 bf16

__device__ __forceinline__ float b2f(u16 h) {
    union { unsigned int u; float f; } v; v.u = ((unsigned int)h) << 16; return v.f;
}
// native cast: compiler emits v_cvt_pk_bf16_f32 (RNE, same as manual form)
__device__ __forceinline__ u16 f2b(float f) {
    return __builtin_bit_cast(u16, (__bf16)f);
}
__device__ __forceinline__ float sigm(float x) { return 1.0f / (1.0f + __expf(-x)); }
__device__ __forceinline__ float tanhfast(float x) { return 1.0f - 2.0f / (__expf(2.0f * x) + 1.0f); }
__device__ __forceinline__ float relu(float x) { return x > 0.0f ? x : 0.0f; }
__device__ __forceinline__ bf16x8 ld8(const u16* p) { return *(const bf16x8*)p; }
__device__ __forceinline__ f32x4 mfma16(bf16x8 a, bf16x8 b, f32x4 c) {
    return __builtin_amdgcn_mfma_f32_16x16x32_bf16(a, b, c, 0, 0, 0);
}

// dtype probe (data is f32): bf16-packed words carry an exponent field in
// bits 7..14; f32 words have mantissa bits there.
__device__ __forceinline__ bool detect_f32(const void* imgp) {
    const unsigned int* w = (const unsigned int*)imgp;
    int hits = 0;
    #pragma unroll
    for (int i = 0; i < 16; ++i) {
        int e0 = (w[i] >> 7) & 0xFF;
        hits += (e0 >= 100 && e0 <= 140) ? 1 : 0;
    }
    return hits < 10;
}

__device__ __forceinline__ float ldin(const void* p, size_t i, bool f32) {
    return f32 ? ((const float*)p)[i] : b2f(((const u16*)p)[i]);
}
__device__ __forceinline__ void stout_nt(void* o, size_t i, float v, bool f32) {
    if (f32) __builtin_nontemporal_store(v, (float*)o + i);
    else ((u16*)o)[i] = f2b(v);
}
// 4-wide vector load, NON-TEMPORAL (streaming data: cx)
__device__ __forceinline__ f32x4 ld4(const void* p, size_t i, bool f32) {
    if (f32) return __builtin_nontemporal_load((const f32x4*)((const float*)p + i));
    u16x4 q = *(const u16x4*)((const u16*)p + i);
    f32x4 r;
    #pragma unroll
    for (int j = 0; j < 4; ++j) r[j] = b2f(q[j]);
    return r;
}
// 4-wide vector load, PLAIN (reused data: biases — keep in cache)
__device__ __forceinline__ f32x4 ld4p(const void* p, size_t i, bool f32) {
    if (f32) return *(const f32x4*)((const float*)p + i);
    u16x4 q = *(const u16x4*)((const u16*)p + i);
    f32x4 r;
    #pragma unroll
    for (int j = 0; j < 4; ++j) r[j] = b2f(q[j]);
    return r;
}
__device__ __forceinline__ void st4(void* o, size_t i, f32x4 v, bool f32) {
    if (f32) __builtin_nontemporal_store(v, (f32x4*)((float*)o + i));
    else {
        u16x4 p;
        #pragma unroll
        for (int j = 0; j < 4; ++j) p[j] = f2b(v[j]);
        *(u16x4*)((u16*)o + i) = p;
    }
}
// load 8 elems, convert to packed bf16 (for staging streams into LDS)
__device__ __forceinline__ u16x8 ldg8b(const void* p, size_t i, bool f32) {
    u16x8 t;
    if (f32) {
        const f32x4* q = (const f32x4*)((const float*)p + i);
        f32x4 a = __builtin_nontemporal_load(q);
        f32x4 b = __builtin_nontemporal_load(q + 1);
        #pragma unroll
        for (int j = 0; j < 4; ++j) { t[j] = f2b(a[j]); t[4 + j] = f2b(b[j]); }
    } else {
        t = *(const u16x8*)((const u16*)p + i);
    }
    return t;
}

// ---- weight pre-conversion + MFMA-frag swizzle ----
// SOURCE-COALESCED iteration (R8, proven): consecutive lanes read consecutive
// 32B of W[N,K]; scattered 16B writes are fire-and-forget.
struct CvtArgs {
    const void* src[10];
    unsigned int nchunk[10];
    unsigned int off8[10];
    unsigned int Kdim[10];
    const void* emb;
    const void* w_ta;
    const void* b_ta;
    const void* det;
};

__global__ __launch_bounds__(256) void cvt_weights(CvtArgs a, u16* ws) {
    const bool f32 = detect_f32(a.det);
    const int p = blockIdx.x;
    if (p == 10) {
        // G table: sigmoid(emb @ w_ta^T + b_ta) for all 4 embeddings -> ws
        if (blockIdx.y == 0) {
            for (int j = threadIdx.x; j < 1024; j += 256) {
                int e = j >> 8, n = j & 255;
                float acc = ldin(a.b_ta, n, f32);
                #pragma unroll
                for (int k = 0; k < 25; ++k)
                    acc += ldin(a.emb, e * 25 + k, f32) * ldin(a.w_ta, n * 25 + k, f32);
                ws[OFF_G + j] = f2b(sigm(acc));
            }
        }
        return;
    }
    const void* s = a.src[p];
    const unsigned int K = a.Kdim[p];
    const unsigned int sh = 31 - __clz((int)(K >> 5));   // log2(KK)
    const unsigned int cpr = K >> 3;                     // 8-elem chunks per row
    const unsigned int csh = sh + 2;                     // log2(cpr)
    const unsigned int n = a.nchunk[p];
    for (unsigned int e = blockIdx.y * blockDim.x + threadIdx.x; e < n;
         e += gridDim.y * blockDim.x) {
        const unsigned int row  = e >> csh;
        const unsigned int colc = e & (cpr - 1u);
        const unsigned int g = ((((row >> 4) << sh) + (colc >> 2)) << 6)
                             + ((colc & 3u) << 4) + (row & 15u);
        const size_t si = ((size_t)e) << 3;              // linear: coalesced
        u16 t[8];
        if (f32) {
            const f32x4* q = (const f32x4*)((const float*)s + si);
            f32x4 va = *q;
            f32x4 vb = *(q + 1);
            #pragma unroll
            for (int j = 0; j < 4; ++j) { t[j] = f2b(va[j]); t[4 + j] = f2b(vb[j]); }
        } else {
            *(u16x8*)t = *(const u16x8*)((const u16*)s + si);
        }
        ((u16x8*)ws)[a.off8[p] + g] = *(u16x8*)t;
    }
}

// TM=64, 16 waves, 1 block/CU (LDS-bound) = 4 waves/SIMD — EXACTLY 4 waves/EU.
// amdgpu_waves_per_eu(4,4) tells the backend occupancy cannot exceed 4/EU, so
// the allocator may use up to 128 VGPRs instead of its default 64-VGPR
// (8 waves/EU) target. R11 showed the 64-cap forced the tile-1 prefetch to
// SPILL (FETCH/WRITE +200/+385 MB of scratch traffic, dur 179->387us); this
// lifts the ceiling. Tile-1 burst moved to t6 (smallest working set; HBM
// latency ~0.4us needs only ~1 phase of lead).
__global__ __launch_bounds__(1024)
__attribute__((amdgpu_waves_per_eu(4, 4)))
void ac_fused(
    const void* __restrict__ img, const int* __restrict__ insn,
    const void* __restrict__ hx_in, const void* __restrict__ cx_in,
    const void* __restrict__ query,
    const void* __restrict__ b_ih, const void* __restrict__ b_hh,
    const void* __restrict__ b_q, const void* __restrict__ b_k,
    const void* __restrict__ b_ba, const void* __restrict__ b_at,
    const void* __restrict__ b_p1, const void* __restrict__ b_p2,
    const void* __restrict__ w_p3, const void* __restrict__ b_p3,
    const void* __restrict__ b_v1, const void* __restrict__ b_v2,
    const void* __restrict__ w_v3, const void* __restrict__ b_v3,
    const u16* __restrict__ wsb, void* __restrict__ out)
{
    __shared__ __align__(16) u16 sGF[TM * LDP];   // gf -> av -> pol2|valh2
    __shared__ __align__(16) u16 sHX0[TM * LDP];  // hx_old -> val -> pol1|valh1
    __shared__ __align__(16) u16 sHX1[TM * LDP];  // hx_new
    __shared__ __align__(16) u16 sKEY[TM * LDP];  // query -> key_ -> attn_weight
    __shared__ __align__(16) u16 sG[4 * LDP];
    __shared__ float sW3[224];                    // staged w_p3 (192) | w_v3 (32)
    __shared__ int sIDX[TM];

    const bool isf32 = detect_f32(img);
    const int tid  = threadIdx.x;
    const int lane = tid & 63;
    const int wv   = tid >> 6;                    // 0..15
    const int l15  = lane & 15;
    const int quad = lane >> 4;
    const int q8   = quad * 8;
    const int q4   = quad * 4;
    const int ln8  = lane * 8;
    const int rowB = blockIdx.x * (2 * TM);       // block covers 2 tiles
    const int nb16 = wv * 16 + q4;                // per-wave N-col base (tile=wv)

    const int r0s = tid >> 5, c0s = (tid & 31) << 3;          // slot 0
    const int r1s = (tid + 1024) >> 5;                        // slot 1 (same c0s)

    // prefetch state (single-buffered: written for tile t, consumed at 0b(t))
    float ivA[8], hvA[8], ivB[8], hvB[8];
    u16x8 qvA, qvB;
    f32x4 cxo[4];
    auto burst = [&](int rb) {
        const size_t base0 = (size_t)(rb + r0s) * 256 + c0s;
        const size_t base1 = (size_t)(rb + r1s) * 256 + c0s;
        #pragma unroll
        for (int m = 0; m < 4; ++m)
            cxo[m] = ld4(cx_in, (size_t)(rb + m * 16 + l15) * 256 + nb16, isf32);
        qvA = ldg8b(query, base0, isf32);
        qvB = ldg8b(query, base1, isf32);
        if (isf32) {
            const f32x4* ip0 = (const f32x4*)((const float*)img + base0);
            const f32x4* hp0 = (const f32x4*)((const float*)hx_in + base0);
            const f32x4* ip1 = (const f32x4*)((const float*)img + base1);
            const f32x4* hp1 = (const f32x4*)((const float*)hx_in + base1);
            f32x4 a0 = __builtin_nontemporal_load(ip0);
            f32x4 a1 = __builtin_nontemporal_load(ip0 + 1);
            f32x4 b0 = __builtin_nontemporal_load(hp0);
            f32x4 b1 = __builtin_nontemporal_load(hp0 + 1);
            f32x4 c0 = __builtin_nontemporal_load(ip1);
            f32x4 c1 = __builtin_nontemporal_load(ip1 + 1);
            f32x4 d0 = __builtin_nontemporal_load(hp1);
            f32x4 d1 = __builtin_nontemporal_load(hp1 + 1);
            #pragma unroll
            for (int j = 0; j < 4; ++j) {
                ivA[j] = a0[j]; ivA[4 + j] = a1[j];
                hvA[j] = b0[j]; hvA[4 + j] = b1[j];
                ivB[j] = c0[j]; ivB[4 + j] = c1[j];
                hvB[j] = d0[j]; hvB[4 + j] = d1[j];
            }
        } else {
            u16x8 i80 = *(const u16x8*)((const u16*)img + base0);
            u16x8 h80 = *(const u16x8*)((const u16*)hx_in + base0);
            u16x8 i81 = *(const u16x8*)((const u16*)img + base1);
            u16x8 h81 = *(const u16x8*)((const u16*)hx_in + base1);
            #pragma unroll
            for (int j = 0; j < 8; ++j) {
                ivA[j] = b2f(i80[j]); hvA[j] = b2f(h80[j]);
                ivB[j] = b2f(i81[j]); hvB[j] = b2f(h81[j]);
            }
        }
    };

    // ---- preamble: tile-0 burst + sIDX + G table ----
    burst(rowB);
    if (tid < TM) sIDX[tid] = insn[rowB + tid];
    sG[(tid >> 8) * LDP + (tid & 255)] = wsb[OFF_G + tid];
    __syncthreads();

    #pragma unroll
    for (int it = 0; it < 2; ++it) {
        const int row0 = rowB + it * TM;

        // ---- phase 0b: gf = img*G[idx], hx_old, query -> LDS ----
        {
            int e0 = sIDX[r0s], e1 = sIDX[r1s];
            u16x8 gv0 = *(const u16x8*)(sG + e0 * LDP + c0s);
            u16x8 gv1 = *(const u16x8*)(sG + e1 * LDP + c0s);
            u16x8 ov0, hvv0, ov1, hvv1;
            #pragma unroll
            for (int j = 0; j < 8; ++j) {
                ov0[j] = f2b(ivA[j] * b2f(gv0[j]));  hvv0[j] = f2b(hvA[j]);
                ov1[j] = f2b(ivB[j] * b2f(gv1[j]));  hvv1[j] = f2b(hvB[j]);
            }
            *(u16x8*)(sGF + r0s * LDP + c0s) = ov0;
            *(u16x8*)(sHX0 + r0s * LDP + c0s) = hvv0;
            *(u16x8*)(sGF + r1s * LDP + c0s) = ov1;
            *(u16x8*)(sHX0 + r1s * LDP + c0s) = hvv1;
            *(u16x8*)(sKEY + r0s * LDP + c0s) = qvA;
            *(u16x8*)(sKEY + r1s * LDP + c0s) = qvB;
        }
        __syncthreads();

        // ---- t1: LSTM gates, swapped: acc = W x act^T, bias-init ----
        {
            int eIdx[4];
            #pragma unroll
            for (int m = 0; m < 4; ++m) eIdx[m] = sIDX[m * 16 + l15];
            const u16* bih0 = wsb + OFF_WIH + ln8;
            const u16* bhh0 = wsb + OFF_WHH + ln8;
            const int c = wv;                     // N-tile 0..15
            f32x4 acc[4][4];
            #pragma unroll
            for (int g = 0; g < 4; ++g) {
                f32x4 bs = ld4p(b_ih, g * 256 + nb16, isf32)
                         + ld4p(b_hh, g * 256 + nb16, isf32);
                #pragma unroll
                for (int m = 0; m < 4; ++m) acc[g][m] = bs;
            }
            #pragma unroll
            for (int kk = 0; kk < 8; ++kk) {      // gf section (ih cols 0..255)
                bf16x8 a[4], b[4];
                #pragma unroll
                for (int m = 0; m < 4; ++m) a[m] = ld8(sGF + (m * 16 + l15) * LDP + kk * 32 + q8);
                #pragma unroll
                for (int g = 0; g < 4; ++g) b[g] = ld8(bih0 + (size_t)((g * 16 + c) * 16 + kk) * 512);
                #pragma unroll
                for (int g = 0; g < 4; ++g)
                    #pragma unroll
                    for (int m = 0; m < 4; ++m) acc[g][m] = mfma16(b[g], a[m], acc[g][m]);
            }
            #pragma unroll
            for (int kk = 0; kk < 8; ++kk) {      // ga section (ih cols 256..511)
                bf16x8 a[4], b[4];
                #pragma unroll
                for (int m = 0; m < 4; ++m) a[m] = ld8(sG + eIdx[m] * LDP + kk * 32 + q8);
                #pragma unroll
                for (int g = 0; g < 4; ++g) b[g] = ld8(bih0 + (size_t)((g * 16 + c) * 16 + 8 + kk) * 512);
                #pragma unroll
                for (int g = 0; g < 4; ++g)
                    #pragma unroll
                    for (int m = 0; m < 4; ++m) acc[g][m] = mfma16(b[g], a[m], acc[g][m]);
            }
            #pragma unroll
            for (int kk = 0; kk < 8; ++kk) {      // hx section (w_hh)
                bf16x8 a[4], b[4];
                #pragma unroll
                for (int m = 0; m < 4; ++m) a[m] = ld8(sHX0 + (m * 16 + l15) * LDP + kk * 32 + q8);
                #pragma unroll
                for (int g = 0; g < 4; ++g) b[g] = ld8(bhh0 + (size_t)((g * 16 + c) * 8 + kk) * 512);
                #pragma unroll
                for (int g = 0; g < 4; ++g)
                    #pragma unroll
                    for (int m = 0; m < 4; ++m) acc[g][m] = mfma16(b[g], a[m], acc[g][m]);
            }
            #pragma unroll
            for (int m = 0; m < 4; ++m) {
                const int batch = m * 16 + l15;
                const size_t gbase = (size_t)(row0 + batch) * 256 + nb16;
                f32x4 hnv, cnv; u16x4 hpk;
                #pragma unroll
                for (int r = 0; r < 4; ++r) {
                    const float iv = sigm(acc[0][m][r]);
                    const float fv = sigm(acc[1][m][r]);
                    const float gv = tanhfast(acc[2][m][r]);
                    const float ov = sigm(acc[3][m][r]);
                    const float cn = fv * cxo[m][r] + iv * gv;
                    const float hn = ov * tanhfast(cn);
                    cnv[r] = cn; hnv[r] = hn; hpk[r] = f2b(hn);
                }
                st4(out, (size_t)(4 * BTOT) + gbase, hnv, isf32);
                st4(out, (size_t)(4 * BTOT) + (size_t)256 * BTOT + gbase, cnv, isf32);
                *(u16x4*)(sHX1 + batch * LDP + nb16) = hpk;
            }
        }
        __syncthreads();

        // ---- t2: cq (query-from-LDS GEMM, lives to t3) + mlp_attn ----
        f32x4 cq[4];                              // crosses the t2->t3 barrier
        {
            {
                f32x4 bq4 = ld4p(b_q, nb16, isf32);
                #pragma unroll
                for (int m = 0; m < 4; ++m) cq[m] = bq4;
            }
            const u16* bq0 = wsb + OFF_WQ + ln8;
            #pragma unroll
            for (int kk = 0; kk < 8; ++kk) {
                bf16x8 aq[4];
                #pragma unroll
                for (int m = 0; m < 4; ++m)
                    aq[m] = ld8(sKEY + (m * 16 + l15) * LDP + kk * 32 + q8);
                bf16x8 bqf = ld8(bq0 + (size_t)(wv * 8 + kk) * 512);
                #pragma unroll
                for (int m = 0; m < 4; ++m) cq[m] = mfma16(bqf, aq[m], cq[m]);
            }
            const u16* bb0 = wsb + OFF_WBA + ln8;
            f32x4 acc[2][4];
            #pragma unroll
            for (int t = 0; t < 2; ++t) {
                f32x4 bb4 = ld4p(b_ba, (wv * 2 + t) * 16 + q4, isf32);
                #pragma unroll
                for (int m = 0; m < 4; ++m) acc[t][m] = bb4;
            }
            #pragma unroll
            for (int kk = 0; kk < 8; ++kk) {      // gf
                bf16x8 a[4], b[2];
                #pragma unroll
                for (int m = 0; m < 4; ++m) a[m] = ld8(sGF + (m * 16 + l15) * LDP + kk * 32 + q8);
                #pragma unroll
                for (int t = 0; t < 2; ++t) b[t] = ld8(bb0 + (size_t)((wv * 2 + t) * 16 + kk) * 512);
                #pragma unroll
                for (int t = 0; t < 2; ++t)
                    #pragma unroll
                    for (int m = 0; m < 4; ++m) acc[t][m] = mfma16(b[t], a[m], acc[t][m]);
            }
            #pragma unroll
            for (int kk = 0; kk < 8; ++kk) {      // hx_new
                bf16x8 a[4], b[2];
                #pragma unroll
                for (int m = 0; m < 4; ++m) a[m] = ld8(sHX1 + (m * 16 + l15) * LDP + kk * 32 + q8);
                #pragma unroll
                for (int t = 0; t < 2; ++t) b[t] = ld8(bb0 + (size_t)((wv * 2 + t) * 16 + 8 + kk) * 512);
                #pragma unroll
                for (int t = 0; t < 2; ++t)
                    #pragma unroll
                    for (int m = 0; m < 4; ++m) acc[t][m] = mfma16(b[t], a[m], acc[t][m]);
            }
            // all waves done READING query from sKEY before overwrite
            __syncthreads();
            #pragma unroll
            for (int t = 0; t < 2; ++t) {
                const int colb = (wv * 2 + t) * 16 + q4;
                u16* dst = (colb < 256) ? (sKEY + colb) : (sHX0 + (colb - 256));
                #pragma unroll
                for (int m = 0; m < 4; ++m) {
                    u16x4 pk;
                    #pragma unroll
                    for (int r = 0; r < 4; ++r) pk[r] = f2b(relu(acc[t][m][r]));
                    *(u16x4*)(dst + (m * 16 + l15) * LDP) = pk;
                }
            }
        }
        __syncthreads();

        // ---- t3: ck GEMM + t4's hx_new half (independent, lives to t4) ----
        f32x4 acc4[4];                            // crosses the t3->t4 barrier
        {
            const u16* bat0 = wsb + OFF_WAT + ln8;
            {
                f32x4 bat4 = ld4p(b_at, nb16, isf32);
                #pragma unroll
                for (int m = 0; m < 4; ++m) acc4[m] = bat4;
            }
            #pragma unroll
            for (int kk = 0; kk < 8; ++kk) {
                bf16x8 a[4];
                #pragma unroll
                for (int m = 0; m < 4; ++m) a[m] = ld8(sHX1 + (m * 16 + l15) * LDP + kk * 32 + q8);
                bf16x8 b = ld8(bat0 + (size_t)(wv * 16 + 8 + kk) * 512);
                #pragma unroll
                for (int m = 0; m < 4; ++m) acc4[m] = mfma16(b, a[m], acc4[m]);
            }
            f32x4 ck[4];
            {
                f32x4 bk4 = ld4p(b_k, nb16, isf32);
                #pragma unroll
                for (int m = 0; m < 4; ++m) ck[m] = bk4;
            }
            const u16* bk0 = wsb + OFF_WK + ln8;
            #pragma unroll
            for (int kk = 0; kk < 8; ++kk) {
                bf16x8 ak[4];
                #pragma unroll
                for (int m = 0; m < 4; ++m) ak[m] = ld8(sKEY + (m * 16 + l15) * LDP + kk * 32 + q8);
                bf16x8 bkf = ld8(bk0 + (size_t)(wv * 8 + kk) * 512);
                #pragma unroll
                for (int m = 0; m < 4; ++m) ck[m] = mfma16(bkf, ak[m], ck[m]);
            }
            #pragma unroll
            for (int m = 0; m < 4; ++m) {
                const int batch = m * 16 + l15;
                u16x4 vv = *(const u16x4*)(sHX0 + batch * LDP + nb16);
                u16x4 pk;
                #pragma unroll
                for (int r = 0; r < 4; ++r) {
                    const float u = tanhfast(relu(cq[m][r]) + relu(ck[m][r]));
                    pk[r] = f2b(u * b2f(vv[r]));
                }
                *(u16x4*)(sGF + batch * LDP + nb16) = pk;
            }
        }
        __syncthreads();

        // ---- t4: av half of attn_weight (hx half already in acc4) -> sKEY ----
        {
            const u16* bat0 = wsb + OFF_WAT + ln8;
            #pragma unroll
            for (int kk = 0; kk < 8; ++kk) {      // av
                bf16x8 a[4];
                #pragma unroll
                for (int m = 0; m < 4; ++m) a[m] = ld8(sGF + (m * 16 + l15) * LDP + kk * 32 + q8);
                bf16x8 b = ld8(bat0 + (size_t)(wv * 16 + kk) * 512);
                #pragma unroll
                for (int m = 0; m < 4; ++m) acc4[m] = mfma16(b, a[m], acc4[m]);
            }
            #pragma unroll
            for (int m = 0; m < 4; ++m) {
                u16x4 pk;
                #pragma unroll
                for (int r = 0; r < 4; ++r) pk[r] = f2b(relu(acc4[m][r]));
                *(u16x4*)(sKEY + (m * 16 + l15) * LDP + nb16) = pk;
            }
        }
        __syncthreads();

        // ---- t5: pol1 / valh1 -> sHX0 (+ stage w_p3/w_v3 for t7, once) ----
        {
            if (it == 0 && tid < 224)
                sW3[tid] = (tid < 192) ? ldin(w_p3, tid, isf32)
                                       : ldin(w_v3, tid - 192, isf32);
            const int m = wv & 3, half = wv >> 2; // m 0..3, half 0..3
            const int batch = m * 16 + l15;
            bf16x8 afr[8];
            #pragma unroll
            for (int kk = 0; kk < 8; ++kk) afr[kk] = ld8(sKEY + batch * LDP + kk * 32 + q8);
            {   // pol1: N=128 (8 tiles), KK=8: tiles half*2+t, bias-init
                f32x4 acc[2];
                #pragma unroll
                for (int t = 0; t < 2; ++t) acc[t] = ld4p(b_p1, (half * 2 + t) * 16 + q4, isf32);
                #pragma unroll
                for (int kk = 0; kk < 8; ++kk)
                    #pragma unroll
                    for (int t = 0; t < 2; ++t)
                        acc[t] = mfma16(ld8(wsb + OFF_WP1 + (size_t)((half * 2 + t) * 8 + kk) * 512 + ln8), afr[kk], acc[t]);
                #pragma unroll
                for (int t = 0; t < 2; ++t) {
                    const int colb = (half * 2 + t) * 16 + q4;
                    u16x4 pk;
                    #pragma unroll
                    for (int r = 0; r < 4; ++r) pk[r] = f2b(relu(acc[t][r]));
                    *(u16x4*)(sHX0 + batch * LDP + colb) = pk;
                }
            }
            {   // valh1: N=64 (4 tiles) -> sHX0 cols 128..191; tile = half
                f32x4 acc = ld4p(b_v1, half * 16 + q4, isf32);
                #pragma unroll
                for (int kk = 0; kk < 8; ++kk)
                    acc = mfma16(ld8(wsb + OFF_WV1 + (size_t)(half * 8 + kk) * 512 + ln8), afr[kk], acc);
                const int colb = half * 16 + q4;
                u16x4 pk;
                #pragma unroll
                for (int r = 0; r < 4; ++r) pk[r] = f2b(relu(acc[r]));
                *(u16x4*)(sHX0 + batch * LDP + 128 + colb) = pk;
            }
        }
        __syncthreads();

        // ---- t6: pol2 / valh2 -> sGF (+ tile-1 burst prefetch) ----
        {
            // PREFETCH TILE-1 HBM BURST here: t6/t7 have the smallest
            // register working sets; ~2 phases (>4us) of lead vs ~0.4us
            // HBM latency. sIDX reload ordered by the t6->t7 barrier.
            if (it == 0) {
                burst(rowB + TM);
                if (tid < TM) sIDX[tid] = insn[rowB + TM + tid];
            }
            const int m = wv & 3, half = wv >> 2; // m 0..3, half 0..3
            const int batch = m * 16 + l15;
            const u16* a0 = sHX0 + batch * LDP;
            bf16x8 ap[4], av2[2];
            #pragma unroll
            for (int kk = 0; kk < 4; ++kk) ap[kk] = ld8(a0 + kk * 32 + q8);
            #pragma unroll
            for (int kk = 0; kk < 2; ++kk) av2[kk] = ld8(a0 + 128 + kk * 32 + q8);
            {   // pol2: KK=4, 4 tiles: tile = half, bias-init
                f32x4 acc = ld4p(b_p2, half * 16 + q4, isf32);
                #pragma unroll
                for (int kk = 0; kk < 4; ++kk)
                    acc = mfma16(ld8(wsb + OFF_WP2 + (size_t)(half * 4 + kk) * 512 + ln8), ap[kk], acc);
                const int colb = half * 16 + q4;
                u16x4 pk;
                #pragma unroll
                for (int r = 0; r < 4; ++r) pk[r] = f2b(relu(acc[r]));
                *(u16x4*)(sGF + batch * LDP + colb) = pk;
            }
            if (half < 2) {   // valh2: KK=2, 2 tiles -> sGF cols 64..95
                f32x4 acc = ld4p(b_v2, half * 16 + q4, isf32);
                #pragma unroll
                for (int kk = 0; kk < 2; ++kk)
                    acc = mfma16(ld8(wsb + OFF_WV2 + (size_t)(half * 2 + kk) * 512 + ln8), av2[kk], acc);
                const int colb = half * 16 + q4;
                u16x4 pk;
                #pragma unroll
                for (int r = 0; r < 4; ++r) pk[r] = f2b(relu(acc[r]));
                *(u16x4*)(sGF + batch * LDP + 64 + colb) = pk;
            }
        }
        __syncthreads();

        // ---- t7: tiny heads (weights from LDS) ----
        if (tid < TM * 4) {
            const int r = tid >> 2, o = tid & 3;
            const int grow = row0 + r;
            const u16* rowp = sGF + r * LDP;
            if (o < 3) {
                float acc = ldin(b_p3, o, isf32);
                #pragma unroll
                for (int k = 0; k < 64; ++k) acc += b2f(rowp[k]) * sW3[o * 64 + k];
                stout_nt(out, (size_t)BTOT + (size_t)grow * 3 + o, acc, isf32);
            } else {
                float acc = ldin(b_v3, 0, isf32);
                #pragma unroll
                for (int k = 0; k < 32; ++k) acc += b2f(rowp[64 + k]) * sW3[192 + k];
                stout_nt(out, (size_t)grow, acc, isf32);
            }
        }
        // protect 0b(it+1) LDS writes against t7 reads
        __syncthreads();
    }
}

extern "C" void kernel_launch(void* const* d_in, const int* in_sizes, int n_in,
                              void* d_out, int out_size, void* d_ws, size_t ws_size,
                              hipStream_t stream) {
    u16* ws = (u16*)d_ws;

    CvtArgs ca;
    const int srcIdx[10] = {8, 9, 12, 14, 16, 18, 20, 22, 26, 28};
    const unsigned int ns[10]   = {524288, 262144, 65536, 65536, 262144, 131072, 32768, 8192, 16384, 2048};
    const unsigned int off[10]  = {OFF_WIH, OFF_WHH, OFF_WQ, OFF_WK, OFF_WBA, OFF_WAT, OFF_WP1, OFF_WP2, OFF_WV1, OFF_WV2};
    const unsigned int kd[10]   = {512, 256, 256, 256, 512, 512, 256, 128, 256, 64};
    for (int i = 0; i < 10; ++i) {
        ca.src[i] = d_in[srcIdx[i]];
        ca.nchunk[i] = ns[i] / 8;
        ca.off8[i] = off[i] / 8;
        ca.Kdim[i] = kd[i];
    }
    ca.emb = d_in[5];
    ca.w_ta = d_in[6];
    ca.b_ta = d_in[7];
    ca.det = d_in[0];
    cvt_weights<<<dim3(11, 64), dim3(256), 0, stream>>>(ca, ws);

    ac_fused<<<dim3(BTOT / (2 * TM)), dim3(1024), 0, stream>>>(
        d_in[0], (const int*)d_in[1], d_in[2], d_in[3], d_in[4],
        d_in[10], d_in[11],           // b_ih, b_hh
        d_in[13], d_in[15],           // b_q, b_k
        d_in[17], d_in[19],           // b_ba, b_at
        d_in[21], d_in[23],           // b_p1, b_p2
        d_in[24], d_in[25],           // w_p, b_p
        d_in[27], d_in[29],           // b_v1, b_v2
        d_in[30], d_in[31],           // w_v, b_v
        (const u16*)d_ws, d_out);
}

// Round 13
// 357.745 us; speedup vs baseline: 1.5449x; 1.5449x over previous
//
#include <hip/hip_runtime.h>

typedef unsigned short u16;
typedef __bf16 bf16x8 __attribute__((ext_vector_type(8)));
typedef float f32x4 __attribute__((ext_vector_type(4)));
typedef u16 u16x8 __attribute__((ext_vector_type(8)));
typedef u16 u16x4 __attribute__((ext_vector_type(4)));

#define TM 64
#define LDP 264          // padded LDS row stride (elems)
#define BTOT 32768

// bf16 frag-swizzled weight layout inside d_ws (element offsets)
#define OFF_WIH 0
#define OFF_WHH 524288
#define OFF_WQ  786432
#define OFF_WK  851968
#define OFF_WBA 917504
#define OFF_WAT 1179648
#define OFF_WP1 1310720
#define OFF_WP2 1343488
#define OFF_WV1 1351680
#define OFF_WV2 1368064
#define OFF_G   1370112   // precomputed gate table: 4 x 256 bf16

__device__ __forceinline__ float b2f(u16 h) {
    union { unsigned int u; float f; } v; v.u = ((unsigned int)h) << 16; return v.f;
}
// native cast: compiler emits packed bf16 cvt (RNE, verified identical R11/R12)
__device__ __forceinline__ u16 f2b(float f) {
    return __builtin_bit_cast(u16, (__bf16)f);
}
__device__ __forceinline__ float sigm(float x) { return 1.0f / (1.0f + __expf(-x)); }
__device__ __forceinline__ float tanhfast(float x) { return 1.0f - 2.0f / (__expf(2.0f * x) + 1.0f); }
__device__ __forceinline__ float relu(float x) { return x > 0.0f ? x : 0.0f; }
__device__ __forceinline__ bf16x8 ld8(const u16* p) { return *(const bf16x8*)p; }
__device__ __forceinline__ f32x4 mfma16(bf16x8 a, bf16x8 b, f32x4 c) {
    return __builtin_amdgcn_mfma_f32_16x16x32_bf16(a, b, c, 0, 0, 0);
}

// dtype probe (data is f32): bf16-packed words carry an exponent field in
// bits 7..14; f32 words have mantissa bits there.
__device__ __forceinline__ bool detect_f32(const void* imgp) {
    const unsigned int* w = (const unsigned int*)imgp;
    int hits = 0;
    #pragma unroll
    for (int i = 0; i < 16; ++i) {
        int e0 = (w[i] >> 7) & 0xFF;
        hits += (e0 >= 100 && e0 <= 140) ? 1 : 0;
    }
    return hits < 10;
}

__device__ __forceinline__ float ldin(const void* p, size_t i, bool f32) {
    return f32 ? ((const float*)p)[i] : b2f(((const u16*)p)[i]);
}
__device__ __forceinline__ void stout_nt(void* o, size_t i, float v, bool f32) {
    if (f32) __builtin_nontemporal_store(v, (float*)o + i);
    else ((u16*)o)[i] = f2b(v);
}
// 4-wide vector load, NON-TEMPORAL (streaming data: cx)
__device__ __forceinline__ f32x4 ld4(const void* p, size_t i, bool f32) {
    if (f32) return __builtin_nontemporal_load((const f32x4*)((const float*)p + i));
    u16x4 q = *(const u16x4*)((const u16*)p + i);
    f32x4 r;
    #pragma unroll
    for (int j = 0; j < 4; ++j) r[j] = b2f(q[j]);
    return r;
}
// 4-wide vector load, PLAIN (reused data: biases — keep in cache)
__device__ __forceinline__ f32x4 ld4p(const void* p, size_t i, bool f32) {
    if (f32) return *(const f32x4*)((const float*)p + i);
    u16x4 q = *(const u16x4*)((const u16*)p + i);
    f32x4 r;
    #pragma unroll
    for (int j = 0; j < 4; ++j) r[j] = b2f(q[j]);
    return r;
}
__device__ __forceinline__ void st4(void* o, size_t i, f32x4 v, bool f32) {
    if (f32) __builtin_nontemporal_store(v, (f32x4*)((float*)o + i));
    else {
        u16x4 p;
        #pragma unroll
        for (int j = 0; j < 4; ++j) p[j] = f2b(v[j]);
        *(u16x4*)((u16*)o + i) = p;
    }
}
// load 8 elems, convert to packed bf16 (for staging streams into LDS)
__device__ __forceinline__ u16x8 ldg8b(const void* p, size_t i, bool f32) {
    u16x8 t;
    if (f32) {
        const f32x4* q = (const f32x4*)((const float*)p + i);
        f32x4 a = __builtin_nontemporal_load(q);
        f32x4 b = __builtin_nontemporal_load(q + 1);
        #pragma unroll
        for (int j = 0; j < 4; ++j) { t[j] = f2b(a[j]); t[4 + j] = f2b(b[j]); }
    } else {
        t = *(const u16x8*)((const u16*)p + i);
    }
    return t;
}

// ---- weight pre-conversion + MFMA-frag swizzle ----
// SOURCE-COALESCED iteration (R8, proven): consecutive lanes read consecutive
// 32B of W[N,K]; scattered 16B writes are fire-and-forget.
struct CvtArgs {
    const void* src[10];
    unsigned int nchunk[10];
    unsigned int off8[10];
    unsigned int Kdim[10];
    const void* emb;
    const void* w_ta;
    const void* b_ta;
    const void* det;
};

__global__ __launch_bounds__(256) void cvt_weights(CvtArgs a, u16* ws) {
    const bool f32 = detect_f32(a.det);
    const int p = blockIdx.x;
    if (p == 10) {
        // G table: sigmoid(emb @ w_ta^T + b_ta) for all 4 embeddings -> ws
        if (blockIdx.y == 0) {
            for (int j = threadIdx.x; j < 1024; j += 256) {
                int e = j >> 8, n = j & 255;
                float acc = ldin(a.b_ta, n, f32);
                #pragma unroll
                for (int k = 0; k < 25; ++k)
                    acc += ldin(a.emb, e * 25 + k, f32) * ldin(a.w_ta, n * 25 + k, f32);
                ws[OFF_G + j] = f2b(sigm(acc));
            }
        }
        return;
    }
    const void* s = a.src[p];
    const unsigned int K = a.Kdim[p];
    const unsigned int sh = 31 - __clz((int)(K >> 5));   // log2(KK)
    const unsigned int cpr = K >> 3;                     // 8-elem chunks per row
    const unsigned int csh = sh + 2;                     // log2(cpr)
    const unsigned int n = a.nchunk[p];
    for (unsigned int e = blockIdx.y * blockDim.x + threadIdx.x; e < n;
         e += gridDim.y * blockDim.x) {
        const unsigned int row  = e >> csh;
        const unsigned int colc = e & (cpr - 1u);
        const unsigned int g = ((((row >> 4) << sh) + (colc >> 2)) << 6)
                             + ((colc & 3u) << 4) + (row & 15u);
        const size_t si = ((size_t)e) << 3;              // linear: coalesced
        u16 t[8];
        if (f32) {
            const f32x4* q = (const f32x4*)((const float*)s + si);
            f32x4 va = *q;
            f32x4 vb = *(q + 1);
            #pragma unroll
            for (int j = 0; j < 4; ++j) { t[j] = f2b(va[j]); t[4 + j] = f2b(vb[j]); }
        } else {
            *(u16x8*)t = *(const u16x8*)((const u16*)s + si);
        }
        ((u16x8*)ws)[a.off8[p] + g] = *(u16x8*)t;
    }
}

// R10 structure (best measured: 179us kernel / 359us wall). TM=64, 16 waves,
// 1 block/CU (LDS-bound) = 4 waves/SIMD, grid 512 (one tile per block).
// Phase 0 BURST-issues every streaming HBM read of the block (img, hx,
// query, cx — ~16 16B loads in flight per thread): Little's-law MLP is the
// proven lever (227->179us). Later phases touch only LDS + L2-resident
// weights. The 2-tile fusion + register prefetch (R11/R12) is closed:
// backend pins this kernel at 64 arch-VGPRs and spills any extra state.
__global__ __launch_bounds__(1024, 2) void ac_fused(
    const void* __restrict__ img, const int* __restrict__ insn,
    const void* __restrict__ hx_in, const void* __restrict__ cx_in,
    const void* __restrict__ query,
    const void* __restrict__ b_ih, const void* __restrict__ b_hh,
    const void* __restrict__ b_q, const void* __restrict__ b_k,
    const void* __restrict__ b_ba, const void* __restrict__ b_at,
    const void* __restrict__ b_p1, const void* __restrict__ b_p2,
    const void* __restrict__ w_p3, const void* __restrict__ b_p3,
    const void* __restrict__ b_v1, const void* __restrict__ b_v2,
    const void* __restrict__ w_v3, const void* __restrict__ b_v3,
    const u16* __restrict__ wsb, void* __restrict__ out)
{
    __shared__ __align__(16) u16 sGF[TM * LDP];   // gf -> av -> pol2|valh2
    __shared__ __align__(16) u16 sHX0[TM * LDP];  // hx_old -> val -> pol1|valh1
    __shared__ __align__(16) u16 sHX1[TM * LDP];  // hx_new
    __shared__ __align__(16) u16 sKEY[TM * LDP];  // query -> key_ -> attn_weight
    __shared__ __align__(16) u16 sG[4 * LDP];
    __shared__ float sW3[224];                    // staged w_p3 (192) | w_v3 (32)
    __shared__ int sIDX[TM];

    const bool isf32 = detect_f32(img);
    const int tid  = threadIdx.x;
    const int lane = tid & 63;
    const int wv   = tid >> 6;                    // 0..15
    const int l15  = lane & 15;
    const int quad = lane >> 4;
    const int q8   = quad * 8;
    const int q4   = quad * 4;
    const int ln8  = lane * 8;
    const int row0 = blockIdx.x * TM;
    const int nb16 = wv * 16 + q4;                // per-wave N-col base (tile=wv)

    // ---- phase 0: BURST-issue every streaming HBM read of this block ----
    const int r0s = tid >> 5, c0s = (tid & 31) << 3;          // slot 0
    const int r1s = (tid + 1024) >> 5;                        // slot 1 (same c0s)
    float iv0[8], hv0[8], iv1[8], hv1[8];
    u16x8 qv0, qv1;
    f32x4 cxo[4];
    {
        const size_t base0 = (size_t)(row0 + r0s) * 256 + c0s;
        const size_t base1 = (size_t)(row0 + r1s) * 256 + c0s;
        // cx in t1-epilogue layout (consumed from regs in t1)
        #pragma unroll
        for (int m = 0; m < 4; ++m)
            cxo[m] = ld4(cx_in, (size_t)(row0 + m * 16 + l15) * 256 + nb16, isf32);
        // query in staging layout (written to sKEY in 0b)
        qv0 = ldg8b(query, base0, isf32);
        qv1 = ldg8b(query, base1, isf32);
        if (isf32) {
            const f32x4* ip0 = (const f32x4*)((const float*)img + base0);
            const f32x4* hp0 = (const f32x4*)((const float*)hx_in + base0);
            const f32x4* ip1 = (const f32x4*)((const float*)img + base1);
            const f32x4* hp1 = (const f32x4*)((const float*)hx_in + base1);
            f32x4 a0 = __builtin_nontemporal_load(ip0);
            f32x4 a1 = __builtin_nontemporal_load(ip0 + 1);
            f32x4 b0 = __builtin_nontemporal_load(hp0);
            f32x4 b1 = __builtin_nontemporal_load(hp0 + 1);
            f32x4 c0 = __builtin_nontemporal_load(ip1);
            f32x4 c1 = __builtin_nontemporal_load(ip1 + 1);
            f32x4 d0 = __builtin_nontemporal_load(hp1);
            f32x4 d1 = __builtin_nontemporal_load(hp1 + 1);
            #pragma unroll
            for (int j = 0; j < 4; ++j) {
                iv0[j] = a0[j]; iv0[4 + j] = a1[j];
                hv0[j] = b0[j]; hv0[4 + j] = b1[j];
                iv1[j] = c0[j]; iv1[4 + j] = c1[j];
                hv1[j] = d0[j]; hv1[4 + j] = d1[j];
            }
        } else {
            u16x8 i80 = *(const u16x8*)((const u16*)img + base0);
            u16x8 h80 = *(const u16x8*)((const u16*)hx_in + base0);
            u16x8 i81 = *(const u16x8*)((const u16*)img + base1);
            u16x8 h81 = *(const u16x8*)((const u16*)hx_in + base1);
            #pragma unroll
            for (int j = 0; j < 8; ++j) {
                iv0[j] = b2f(i80[j]); hv0[j] = b2f(h80[j]);
                iv1[j] = b2f(i81[j]); hv1[j] = b2f(h81[j]);
            }
        }
    }
    if (tid < TM) sIDX[tid] = insn[row0 + tid];
    sG[(tid >> 8) * LDP + (tid & 255)] = wsb[OFF_G + tid];
    __syncthreads();

    // ---- phase 0b: gf = img*G[idx], hx_old, query -> LDS ----
    {
        int e0 = sIDX[r0s], e1 = sIDX[r1s];
        u16x8 gv0 = *(const u16x8*)(sG + e0 * LDP + c0s);
        u16x8 gv1 = *(const u16x8*)(sG + e1 * LDP + c0s);
        u16x8 ov0, hvv0, ov1, hvv1;
        #pragma unroll
        for (int j = 0; j < 8; ++j) {
            ov0[j] = f2b(iv0[j] * b2f(gv0[j]));  hvv0[j] = f2b(hv0[j]);
            ov1[j] = f2b(iv1[j] * b2f(gv1[j]));  hvv1[j] = f2b(hv1[j]);
        }
        *(u16x8*)(sGF + r0s * LDP + c0s) = ov0;
        *(u16x8*)(sHX0 + r0s * LDP + c0s) = hvv0;
        *(u16x8*)(sGF + r1s * LDP + c0s) = ov1;
        *(u16x8*)(sHX0 + r1s * LDP + c0s) = hvv1;
        *(u16x8*)(sKEY + r0s * LDP + c0s) = qv0;
        *(u16x8*)(sKEY + r1s * LDP + c0s) = qv1;
    }
    __syncthreads();

    // ---- t1: LSTM gates, swapped: acc = W x act^T, bias-init ----
    {
        int eIdx[4];
        #pragma unroll
        for (int m = 0; m < 4; ++m) eIdx[m] = sIDX[m * 16 + l15];
        const u16* bih0 = wsb + OFF_WIH + ln8;
        const u16* bhh0 = wsb + OFF_WHH + ln8;
        const int c = wv;                         // N-tile 0..15
        f32x4 acc[4][4];
        #pragma unroll
        for (int g = 0; g < 4; ++g) {
            f32x4 bs = ld4p(b_ih, g * 256 + nb16, isf32)
                     + ld4p(b_hh, g * 256 + nb16, isf32);
            #pragma unroll
            for (int m = 0; m < 4; ++m) acc[g][m] = bs;
        }
        #pragma unroll
        for (int kk = 0; kk < 8; ++kk) {          // gf section (ih cols 0..255)
            bf16x8 a[4], b[4];
            #pragma unroll
            for (int m = 0; m < 4; ++m) a[m] = ld8(sGF + (m * 16 + l15) * LDP + kk * 32 + q8);
            #pragma unroll
            for (int g = 0; g < 4; ++g) b[g] = ld8(bih0 + (size_t)((g * 16 + c) * 16 + kk) * 512);
            #pragma unroll
            for (int g = 0; g < 4; ++g)
                #pragma unroll
                for (int m = 0; m < 4; ++m) acc[g][m] = mfma16(b[g], a[m], acc[g][m]);
        }
        #pragma unroll
        for (int kk = 0; kk < 8; ++kk) {          // ga section (ih cols 256..511)
            bf16x8 a[4], b[4];
            #pragma unroll
            for (int m = 0; m < 4; ++m) a[m] = ld8(sG + eIdx[m] * LDP + kk * 32 + q8);
            #pragma unroll
            for (int g = 0; g < 4; ++g) b[g] = ld8(bih0 + (size_t)((g * 16 + c) * 16 + 8 + kk) * 512);
            #pragma unroll
            for (int g = 0; g < 4; ++g)
                #pragma unroll
                for (int m = 0; m < 4; ++m) acc[g][m] = mfma16(b[g], a[m], acc[g][m]);
        }
        #pragma unroll
        for (int kk = 0; kk < 8; ++kk) {          // hx section (w_hh)
            bf16x8 a[4], b[4];
            #pragma unroll
            for (int m = 0; m < 4; ++m) a[m] = ld8(sHX0 + (m * 16 + l15) * LDP + kk * 32 + q8);
            #pragma unroll
            for (int g = 0; g < 4; ++g) b[g] = ld8(bhh0 + (size_t)((g * 16 + c) * 8 + kk) * 512);
            #pragma unroll
            for (int g = 0; g < 4; ++g)
                #pragma unroll
                for (int m = 0; m < 4; ++m) acc[g][m] = mfma16(b[g], a[m], acc[g][m]);
        }
        #pragma unroll
        for (int m = 0; m < 4; ++m) {
            const int batch = m * 16 + l15;
            const size_t gbase = (size_t)(row0 + batch) * 256 + nb16;
            f32x4 hnv, cnv; u16x4 hpk;
            #pragma unroll
            for (int r = 0; r < 4; ++r) {
                const float iv = sigm(acc[0][m][r]);
                const float fv = sigm(acc[1][m][r]);
                const float gv = tanhfast(acc[2][m][r]);
                const float ov = sigm(acc[3][m][r]);
                const float cn = fv * cxo[m][r] + iv * gv;
                const float hn = ov * tanhfast(cn);
                cnv[r] = cn; hnv[r] = hn; hpk[r] = f2b(hn);
            }
            st4(out, (size_t)(4 * BTOT) + gbase, hnv, isf32);
            st4(out, (size_t)(4 * BTOT) + (size_t)256 * BTOT + gbase, cnv, isf32);
            *(u16x4*)(sHX1 + batch * LDP + nb16) = hpk;
        }
    }
    __syncthreads();

    // ---- t2: cq (query-from-LDS GEMM, lives to t3) + mlp_attn ----
    f32x4 cq[4];                                  // crosses the t2->t3 barrier
    {
        // cq: query frags from sKEY (LDS). Bias-init with b_q.
        {
            f32x4 bq4 = ld4p(b_q, nb16, isf32);
            #pragma unroll
            for (int m = 0; m < 4; ++m) cq[m] = bq4;
        }
        const u16* bq0 = wsb + OFF_WQ + ln8;
        #pragma unroll
        for (int kk = 0; kk < 8; ++kk) {
            bf16x8 aq[4];
            #pragma unroll
            for (int m = 0; m < 4; ++m)
                aq[m] = ld8(sKEY + (m * 16 + l15) * LDP + kk * 32 + q8);
            bf16x8 bqf = ld8(bq0 + (size_t)(wv * 8 + kk) * 512);
            #pragma unroll
            for (int m = 0; m < 4; ++m) cq[m] = mfma16(bqf, aq[m], cq[m]);
        }
        // t2 main: bias-init accumulators
        const u16* bb0 = wsb + OFF_WBA + ln8;
        f32x4 acc[2][4];
        #pragma unroll
        for (int t = 0; t < 2; ++t) {
            f32x4 bb4 = ld4p(b_ba, (wv * 2 + t) * 16 + q4, isf32);
            #pragma unroll
            for (int m = 0; m < 4; ++m) acc[t][m] = bb4;
        }
        #pragma unroll
        for (int kk = 0; kk < 8; ++kk) {          // gf
            bf16x8 a[4], b[2];
            #pragma unroll
            for (int m = 0; m < 4; ++m) a[m] = ld8(sGF + (m * 16 + l15) * LDP + kk * 32 + q8);
            #pragma unroll
            for (int t = 0; t < 2; ++t) b[t] = ld8(bb0 + (size_t)((wv * 2 + t) * 16 + kk) * 512);
            #pragma unroll
            for (int t = 0; t < 2; ++t)
                #pragma unroll
                for (int m = 0; m < 4; ++m) acc[t][m] = mfma16(b[t], a[m], acc[t][m]);
        }
        #pragma unroll
        for (int kk = 0; kk < 8; ++kk) {          // hx_new
            bf16x8 a[4], b[2];
            #pragma unroll
            for (int m = 0; m < 4; ++m) a[m] = ld8(sHX1 + (m * 16 + l15) * LDP + kk * 32 + q8);
            #pragma unroll
            for (int t = 0; t < 2; ++t) b[t] = ld8(bb0 + (size_t)((wv * 2 + t) * 16 + 8 + kk) * 512);
            #pragma unroll
            for (int t = 0; t < 2; ++t)
                #pragma unroll
                for (int m = 0; m < 4; ++m) acc[t][m] = mfma16(b[t], a[m], acc[t][m]);
        }
        // all waves done READING query from sKEY before any wave overwrites it
        __syncthreads();
        #pragma unroll
        for (int t = 0; t < 2; ++t) {
            const int colb = (wv * 2 + t) * 16 + q4;
            u16* dst = (colb < 256) ? (sKEY + colb) : (sHX0 + (colb - 256));
            #pragma unroll
            for (int m = 0; m < 4; ++m) {
                u16x4 pk;
                #pragma unroll
                for (int r = 0; r < 4; ++r) pk[r] = f2b(relu(acc[t][m][r]));
                *(u16x4*)(dst + (m * 16 + l15) * LDP) = pk;
            }
        }
    }
    __syncthreads();

    // ---- t3: ck GEMM + t4's hx_new half (independent, lives to t4) ----
    f32x4 acc4[4];                                // crosses the t3->t4 barrier
    {
        const u16* bat0 = wsb + OFF_WAT + ln8;
        // t4-hx half: deps are sHX1 (stable since t1) + ws. Bias-init b_at.
        {
            f32x4 bat4 = ld4p(b_at, nb16, isf32);
            #pragma unroll
            for (int m = 0; m < 4; ++m) acc4[m] = bat4;
        }
        #pragma unroll
        for (int kk = 0; kk < 8; ++kk) {
            bf16x8 a[4];
            #pragma unroll
            for (int m = 0; m < 4; ++m) a[m] = ld8(sHX1 + (m * 16 + l15) * LDP + kk * 32 + q8);
            bf16x8 b = ld8(bat0 + (size_t)(wv * 16 + 8 + kk) * 512);
            #pragma unroll
            for (int m = 0; m < 4; ++m) acc4[m] = mfma16(b, a[m], acc4[m]);
        }
        // ck: key_ @ w_k^T, bias-init b_k
        f32x4 ck[4];
        {
            f32x4 bk4 = ld4p(b_k, nb16, isf32);
            #pragma unroll
            for (int m = 0; m < 4; ++m) ck[m] = bk4;
        }
        const u16* bk0 = wsb + OFF_WK + ln8;
        #pragma unroll
        for (int kk = 0; kk < 8; ++kk) {
            bf16x8 ak[4];
            #pragma unroll
            for (int m = 0; m < 4; ++m) ak[m] = ld8(sKEY + (m * 16 + l15) * LDP + kk * 32 + q8);
            bf16x8 bkf = ld8(bk0 + (size_t)(wv * 8 + kk) * 512);
            #pragma unroll
            for (int m = 0; m < 4; ++m) ck[m] = mfma16(bkf, ak[m], ck[m]);
        }
        // epilogue: u_t * val -> attention_vector (sGF)
        #pragma unroll
        for (int m = 0; m < 4; ++m) {
            const int batch = m * 16 + l15;
            u16x4 vv = *(const u16x4*)(sHX0 + batch * LDP + nb16);
            u16x4 pk;
            #pragma unroll
            for (int r = 0; r < 4; ++r) {
                const float u = tanhfast(relu(cq[m][r]) + relu(ck[m][r]));
                pk[r] = f2b(u * b2f(vv[r]));
            }
            *(u16x4*)(sGF + batch * LDP + nb16) = pk;
        }
    }
    __syncthreads();

    // ---- t4: av half of attn_weight (hx half already in acc4) -> sKEY ----
    {
        const u16* bat0 = wsb + OFF_WAT + ln8;
        #pragma unroll
        for (int kk = 0; kk < 8; ++kk) {          // av
            bf16x8 a[4];
            #pragma unroll
            for (int m = 0; m < 4; ++m) a[m] = ld8(sGF + (m * 16 + l15) * LDP + kk * 32 + q8);
            bf16x8 b = ld8(bat0 + (size_t)(wv * 16 + kk) * 512);
            #pragma unroll
            for (int m = 0; m < 4; ++m) acc4[m] = mfma16(b, a[m], acc4[m]);
        }
        #pragma unroll
        for (int m = 0; m < 4; ++m) {
            u16x4 pk;
            #pragma unroll
            for (int r = 0; r < 4; ++r) pk[r] = f2b(relu(acc4[m][r]));
            *(u16x4*)(sKEY + (m * 16 + l15) * LDP + nb16) = pk;
        }
    }
    __syncthreads();

    // ---- t5: pol1 / valh1 -> sHX0 (+ stage w_p3/w_v3 for t7) ----
    {
        if (tid < 224)
            sW3[tid] = (tid < 192) ? ldin(w_p3, tid, isf32)
                                   : ldin(w_v3, tid - 192, isf32);
        const int m = wv & 3, half = wv >> 2;     // m 0..3, half 0..3
        const int batch = m * 16 + l15;
        bf16x8 afr[8];
        #pragma unroll
        for (int kk = 0; kk < 8; ++kk) afr[kk] = ld8(sKEY + batch * LDP + kk * 32 + q8);
        {   // pol1: N=128 (8 tiles), KK=8: tiles half*2+t, bias-init
            f32x4 acc[2];
            #pragma unroll
            for (int t = 0; t < 2; ++t) acc[t] = ld4p(b_p1, (half * 2 + t) * 16 + q4, isf32);
            #pragma unroll
            for (int kk = 0; kk < 8; ++kk)
                #pragma unroll
                for (int t = 0; t < 2; ++t)
                    acc[t] = mfma16(ld8(wsb + OFF_WP1 + (size_t)((half * 2 + t) * 8 + kk) * 512 + ln8), afr[kk], acc[t]);
            #pragma unroll
            for (int t = 0; t < 2; ++t) {
                const int colb = (half * 2 + t) * 16 + q4;
                u16x4 pk;
                #pragma unroll
                for (int r = 0; r < 4; ++r) pk[r] = f2b(relu(acc[t][r]));
                *(u16x4*)(sHX0 + batch * LDP + colb) = pk;
            }
        }
        {   // valh1: N=64 (4 tiles) -> sHX0 cols 128..191; tile = half
            f32x4 acc = ld4p(b_v1, half * 16 + q4, isf32);
            #pragma unroll
            for (int kk = 0; kk < 8; ++kk)
                acc = mfma16(ld8(wsb + OFF_WV1 + (size_t)(half * 8 + kk) * 512 + ln8), afr[kk], acc);
            const int colb = half * 16 + q4;
            u16x4 pk;
            #pragma unroll
            for (int r = 0; r < 4; ++r) pk[r] = f2b(relu(acc[r]));
            *(u16x4*)(sHX0 + batch * LDP + 128 + colb) = pk;
        }
    }
    __syncthreads();

    // ---- t6: pol2 (K=128,N=64), valh2 (K=64,N=32) -> sGF ----
    {
        const int m = wv & 3, half = wv >> 2;     // m 0..3, half 0..3
        const int batch = m * 16 + l15;
        const u16* a0 = sHX0 + batch * LDP;
        bf16x8 ap[4], av2[2];
        #pragma unroll
        for (int kk = 0; kk < 4; ++kk) ap[kk] = ld8(a0 + kk * 32 + q8);
        #pragma unroll
        for (int kk = 0; kk < 2; ++kk) av2[kk] = ld8(a0 + 128 + kk * 32 + q8);
        {   // pol2: KK=4, 4 tiles: tile = half, bias-init
            f32x4 acc = ld4p(b_p2, half * 16 + q4, isf32);
            #pragma unroll
            for (int kk = 0; kk < 4; ++kk)
                acc = mfma16(ld8(wsb + OFF_WP2 + (size_t)(half * 4 + kk) * 512 + ln8), ap[kk], acc);
            const int colb = half * 16 + q4;
            u16x4 pk;
            #pragma unroll
            for (int r = 0; r < 4; ++r) pk[r] = f2b(relu(acc[r]));
            *(u16x4*)(sGF + batch * LDP + colb) = pk;
        }
        if (half < 2) {   // valh2: KK=2, 2 tiles: tile = half -> sGF cols 64..95
            f32x4 acc = ld4p(b_v2, half * 16 + q4, isf32);
            #pragma unroll
            for (int kk = 0; kk < 2; ++kk)
                acc = mfma16(ld8(wsb + OFF_WV2 + (size_t)(half * 2 + kk) * 512 + ln8), av2[kk], acc);
            const int colb = half * 16 + q4;
            u16x4 pk;
            #pragma unroll
            for (int r = 0; r < 4; ++r) pk[r] = f2b(relu(acc[r]));
            *(u16x4*)(sGF + batch * LDP + 64 + colb) = pk;
        }
    }
    __syncthreads();

    // ---- t7: tiny heads (weights from LDS) ----
    if (tid < TM * 4) {
        const int r = tid >> 2, o = tid & 3;
        const int grow = row0 + r;
        const u16* rowp = sGF + r * LDP;
        if (o < 3) {
            float acc = ldin(b_p3, o, isf32);
            #pragma unroll
            for (int k = 0; k < 64; ++k) acc += b2f(rowp[k]) * sW3[o * 64 + k];
            stout_nt(out, (size_t)BTOT + (size_t)grow * 3 + o, acc, isf32);
        } else {
            float acc = ldin(b_v3, 0, isf32);
            #pragma unroll
            for (int k = 0; k < 32; ++k) acc += b2f(rowp[64 + k]) * sW3[192 + k];
            stout_nt(out, (size_t)grow, acc, isf32);
        }
    }
}

extern "C" void kernel_launch(void* const* d_in, const int* in_sizes, int n_in,
                              void* d_out, int out_size, void* d_ws, size_t ws_size,
                              hipStream_t stream) {
    u16* ws = (u16*)d_ws;

    CvtArgs ca;
    const int srcIdx[10] = {8, 9, 12, 14, 16, 18, 20, 22, 26, 28};
    const unsigned int ns[10]   = {524288, 262144, 65536, 65536, 262144, 131072, 32768, 8192, 16384, 2048};
    const unsigned int off[10]  = {OFF_WIH, OFF_WHH, OFF_WQ, OFF_WK, OFF_WBA, OFF_WAT, OFF_WP1, OFF_WP2, OFF_WV1, OFF_WV2};
    const unsigned int kd[10]   = {512, 256, 256, 256, 512, 512, 256, 128, 256, 64};
    for (int i = 0; i < 10; ++i) {
        ca.src[i] = d_in[srcIdx[i]];
        ca.nchunk[i] = ns[i] / 8;
        ca.off8[i] = off[i] / 8;
        ca.Kdim[i] = kd[i];
    }
    ca.emb = d_in[5];
    ca.w_ta = d_in[6];
    ca.b_ta = d_in[7];
    ca.det = d_in[0];
    cvt_weights<<<dim3(11, 64), dim3(256), 0, stream>>>(ca, ws);

    ac_fused<<<dim3(BTOT / TM), dim3(1024), 0, stream>>>(
        d_in[0], (const int*)d_in[1], d_in[2], d_in[3], d_in[4],
        d_in[10], d_in[11],           // b_ih, b_hh
        d_in[13], d_in[15],           // b_q, b_k
        d_in[17], d_in[19],           // b_ba, b_at
        d_in[21], d_in[23],           // b_p1, b_p2
        d_in[24], d_in[25],           // w_p, b_p
        d_in[27], d_in[29],           // b_v1, b_v2
        d_in[30], d_in[31],           // w_v, b_v
        (const u16*)d_ws, d_out);
}